// Round 1
// baseline (699.444 us; speedup 1.0000x reference)
//
#include <hip/hip_runtime.h>
#include <math.h>

// Problem constants
#define NB      8192
#define NIN     64
#define NOUT    128
#define NHID    32
#define NTGT    2
#define NEXO    3
#define NSER    5
#define EXROWS  (NIN + NOUT)   // 192

#define BT 32   // batch elements per block in the recurrent kernel

__device__ __forceinline__ float sigmoidf(float x) {
    return 1.0f / (1.0f + __expf(-x));
}

// -------------------------------------------------------------------------
// Kernel A: precompute exogenous contributions for every (b, i).
// E[b,i,o] = b1[o] + b3[o]
//          + sum_{t,e} W1[o, t*5+2+e] * exog[b, i+t, e]
//          + sum_{e,h} W3[o, (2+e)*32+h] * sigmoid(b2[2+e,h] + sum_t W2[2+e,h,t]*exog[b,i+t,e])
// Written into d_out (same shape as final output); kernel B reads & overwrites.
// -------------------------------------------------------------------------
__global__ __launch_bounds__(128) void narx_exog_kernel(
    const float* __restrict__ exog,
    const float* __restrict__ W1, const float* __restrict__ b1,
    const float* __restrict__ W2, const float* __restrict__ b2,
    const float* __restrict__ W3, const float* __restrict__ b3,
    float* __restrict__ E)
{
    __shared__ float exs[NEXO][EXROWS];   // [e][t] transposed for conflict-free reads
    const int b = blockIdx.x;
    const int i = threadIdx.x;            // 0..127 (one step per thread)
    const float* exb = exog + (size_t)b * (EXROWS * NEXO);

    for (int idx = threadIdx.x; idx < EXROWS * NEXO; idx += 128) {
        int tt = idx / 3;
        int e  = idx - tt * 3;
        exs[e][tt] = exb[idx];
    }
    __syncthreads();

    float acc0 = b1[0] + b3[0];
    float acc1 = b1[1] + b3[1];

    #pragma unroll
    for (int e = 0; e < NEXO; ++e) {
        float ex[NIN];
        #pragma unroll
        for (int t = 0; t < NIN; ++t) ex[t] = exs[e][i + t];

        // out1 exog part
        #pragma unroll 8
        for (int t = 0; t < NIN; ++t) {
            acc0 += W1[t * 5 + 2 + e] * ex[t];
            acc1 += W1[320 + t * 5 + 2 + e] * ex[t];
        }

        const float* W2s = W2 + (2 + e) * (NHID * NIN);
        const float* b2s = b2 + (2 + e) * NHID;
        const float* W3a = W3 + (2 + e) * NHID;          // row o=0
        const float* W3b = W3 + 160 + (2 + e) * NHID;    // row o=1

        #pragma unroll 4
        for (int h = 0; h < NHID; ++h) {
            float hacc = b2s[h];
            #pragma unroll
            for (int t = 0; t < NIN; ++t) hacc += W2s[h * NIN + t] * ex[t];
            float sig = sigmoidf(hacc);
            acc0 += W3a[h] * sig;
            acc1 += W3b[h] * sig;
        }
    }

    size_t o = ((size_t)b * NOUT + i) * NTGT;
    E[o]     = acc0;
    E[o + 1] = acc1;
}

// -------------------------------------------------------------------------
// Kernel B: the recurrence. 32 batch elements per block, 256 threads.
// y[s][t][bl] holds the full target sequence (64 init + 128 preds) in LDS.
// Thread map: p = tid&31 selects a pair of hidden units (series sN = p>>4,
// h = (p&15)*2 + {0,1}); q = tid>>5 selects a quad of batch elements.
// -------------------------------------------------------------------------
__global__ __launch_bounds__(256, 2) void narx_recur_kernel(
    const float* __restrict__ target,
    const float* __restrict__ W1,
    const float* __restrict__ W2, const float* __restrict__ b2,
    const float* __restrict__ W3,
    float* __restrict__ out)   // holds E on entry, final preds on exit
{
    __shared__ float y[NTGT][EXROWS][BT];
    __shared__ float w1t[NIN][2][2];   // [t][s][o] = W1[o, t*5+s]

    const int tid = threadIdx.x;
    const int p = tid & 31;
    const int q = tid >> 5;            // 0..7 -> batch quad
    const int b0 = blockIdx.x * BT;

    // initial window: target (B,64,2) -> y[s][t][bl]
    for (int idx = tid; idx < BT * NIN * NTGT; idx += 256) {
        int bl = idx >> 7;
        int r  = idx & 127;            // r = t*2 + s
        y[r & 1][r >> 1][bl] = target[(size_t)(b0 + bl) * (NIN * NTGT) + r];
    }
    // w1t (256 entries, one per thread)
    {
        int t = tid >> 2, s = (tid >> 1) & 1, o = tid & 1;
        w1t[t][s][o] = W1[o * 320 + t * 5 + s];
    }

    // per-thread W2 rows (target series only) in registers
    const int sN = p >> 4;
    const int h0 = (p & 15) * 2;
    float w0[NIN], w1r[NIN];
    const float* W2a = W2 + sN * (NHID * NIN) + h0 * NIN;
    #pragma unroll
    for (int t = 0; t < NIN; ++t) { w0[t] = W2a[t]; w1r[t] = W2a[NIN + t]; }
    const float bb0 = b2[sN * NHID + h0];
    const float bb1 = b2[sN * NHID + h0 + 1];
    // W3 columns for this thread's two hidden units
    const float w3_00 = W3[sN * 32 + h0];
    const float w3_01 = W3[sN * 32 + h0 + 1];
    const float w3_10 = W3[160 + sN * 32 + h0];
    const float w3_11 = W3[160 + sN * 32 + h0 + 1];

    __syncthreads();

    for (int i = 0; i < NOUT; ++i) {
        // ---- h = W2_target @ window for 2 hidden units x 4 batch ----
        float a00 = bb0, a01 = bb0, a02 = bb0, a03 = bb0;
        float a10 = bb1, a11 = bb1, a12 = bb1, a13 = bb1;
        #pragma unroll
        for (int t = 0; t < NIN; ++t) {
            float4 yv = *(const float4*)&y[sN][i + t][q * 4];
            float wa = w0[t], wb = w1r[t];
            a00 += wa * yv.x; a01 += wa * yv.y; a02 += wa * yv.z; a03 += wa * yv.w;
            a10 += wb * yv.x; a11 += wb * yv.y; a12 += wb * yv.z; a13 += wb * yv.w;
        }
        float s00 = sigmoidf(a00), s01 = sigmoidf(a01), s02 = sigmoidf(a02), s03 = sigmoidf(a03);
        float s10 = sigmoidf(a10), s11 = sigmoidf(a11), s12 = sigmoidf(a12), s13 = sigmoidf(a13);

        // out2 partials [o][j]
        float t00 = w3_00 * s00 + w3_01 * s10;
        float t01 = w3_00 * s01 + w3_01 * s11;
        float t02 = w3_00 * s02 + w3_01 * s12;
        float t03 = w3_00 * s03 + w3_01 * s13;
        float t10 = w3_10 * s00 + w3_11 * s10;
        float t11 = w3_10 * s01 + w3_11 * s11;
        float t12 = w3_10 * s02 + w3_11 * s12;
        float t13 = w3_10 * s03 + w3_11 * s13;

        // out1 partials: lane p covers window rows t = 2p, 2p+1
        #pragma unroll
        for (int dt = 0; dt < 2; ++dt) {
            int t = 2 * p + dt;
            float4 ya = *(const float4*)&y[0][i + t][q * 4];
            float4 yb = *(const float4*)&y[1][i + t][q * 4];
            float4 wv = *(const float4*)&w1t[t][0][0];  // {s0o0, s0o1, s1o0, s1o1}
            t00 += wv.x * ya.x + wv.z * yb.x;
            t10 += wv.y * ya.x + wv.w * yb.x;
            t01 += wv.x * ya.y + wv.z * yb.y;
            t11 += wv.y * ya.y + wv.w * yb.y;
            t02 += wv.x * ya.z + wv.z * yb.z;
            t12 += wv.y * ya.z + wv.w * yb.z;
            t03 += wv.x * ya.w + wv.z * yb.w;
            t13 += wv.y * ya.w + wv.w * yb.w;
        }

        // butterfly reduce across the 32 p-lanes (q is constant per half-wave)
        #pragma unroll
        for (int off = 16; off >= 1; off >>= 1) {
            t00 += __shfl_xor(t00, off, 32);
            t01 += __shfl_xor(t01, off, 32);
            t02 += __shfl_xor(t02, off, 32);
            t03 += __shfl_xor(t03, off, 32);
            t10 += __shfl_xor(t10, off, 32);
            t11 += __shfl_xor(t11, off, 32);
            t12 += __shfl_xor(t12, off, 32);
            t13 += __shfl_xor(t13, off, 32);
        }

        if (p == 0) {
            float r0[4] = { t00, t01, t02, t03 };
            float r1[4] = { t10, t11, t12, t13 };
            #pragma unroll
            for (int j = 0; j < 4; ++j) {
                int bl = q * 4 + j;
                size_t base = ((size_t)(b0 + bl) * NOUT + i) * NTGT;
                float p0 = r0[j] + out[base]     + y[0][i + 63][bl];
                float p1 = r1[j] + out[base + 1] + y[1][i + 63][bl];
                out[base]     = p0;
                out[base + 1] = p1;
                y[0][i + 64][bl] = p0;
                y[1][i + 64][bl] = p1;
            }
        }
        __syncthreads();
    }
}

extern "C" void kernel_launch(void* const* d_in, const int* in_sizes, int n_in,
                              void* d_out, int out_size, void* d_ws, size_t ws_size,
                              hipStream_t stream) {
    (void)in_sizes; (void)n_in; (void)out_size; (void)d_ws; (void)ws_size;
    const float* target = (const float*)d_in[0];
    const float* exog   = (const float*)d_in[1];
    const float* W1     = (const float*)d_in[2];
    const float* b1     = (const float*)d_in[3];
    const float* W2     = (const float*)d_in[4];
    const float* b2     = (const float*)d_in[5];
    const float* W3     = (const float*)d_in[6];
    const float* b3     = (const float*)d_in[7];
    float* out = (float*)d_out;

    hipLaunchKernelGGL(narx_exog_kernel, dim3(NB), dim3(128), 0, stream,
                       exog, W1, b1, W2, b2, W3, b3, out);
    hipLaunchKernelGGL(narx_recur_kernel, dim3(NB / BT), dim3(256), 0, stream,
                       target, W1, W2, b2, W3, out);
}

// Round 2
// 577.849 us; speedup vs baseline: 1.2104x; 1.2104x over previous
//
#include <hip/hip_runtime.h>
#include <math.h>

#define NB 8192
#define NIN 64
#define NOUT 128
#define NHID 32
#define NEXO 3
#define EXROWS 192
#define NTGT 2

__device__ __forceinline__ float sigmoidf(float x) {
    return 1.0f / (1.0f + __expf(-x));
}

// -------------------------------------------------------------------------
// Kernel A: exogenous contributions E[b,i,o] (includes b1+b3), written to out.
// Phase 1: thread (h=tid>>3, ic=tid&7) computes sigmoid(W2[2+e][h] . exog
//          window) for 16 i-positions via a register sliding window.
// Phase 3: thread (i=tid>>1, half=tid&1) assembles out1_exo + out2_exo.
// -------------------------------------------------------------------------
__global__ __launch_bounds__(256) void narx_exog_kernel(
    const float* __restrict__ exog,
    const float* __restrict__ W1, const float* __restrict__ b1,
    const float* __restrict__ W2, const float* __restrict__ b2,
    const float* __restrict__ W3, const float* __restrict__ b3,
    float* __restrict__ E)
{
    __shared__ __align__(16) float exs[NEXO][EXROWS];   // [e][t]
    __shared__ __align__(16) float sig[96][132];        // [u][i], 132: 16B-aligned rows

    const int tid = threadIdx.x;
    const int b = blockIdx.x;
    const float* exb = exog + (size_t)b * (EXROWS * NEXO);

    for (int idx = tid; idx < EXROWS * NEXO; idx += 256) {
        int t = idx / 3;
        int e = idx - t * 3;
        exs[e][t] = exb[idx];
    }
    __syncthreads();

    const int h  = tid >> 3;   // 0..31
    const int ic = tid & 7;    // 0..7
    const int i0 = ic * 16;

    #pragma unroll 1
    for (int e = 0; e < NEXO; ++e) {
        const float* wrow = W2 + ((2 + e) * NHID + h) * NIN;
        float w[NIN];
        #pragma unroll
        for (int t4 = 0; t4 < 16; ++t4) {
            float4 wv = *(const float4*)(wrow + t4 * 4);
            w[t4*4+0] = wv.x; w[t4*4+1] = wv.y; w[t4*4+2] = wv.z; w[t4*4+3] = wv.w;
        }
        const float bb = b2[(2 + e) * NHID + h];
        float acc[16];
        #pragma unroll
        for (int i = 0; i < 16; ++i) acc[i] = bb;
        float exw[16];
        #pragma unroll
        for (int i4 = 0; i4 < 4; ++i4) {
            float4 xv = *(const float4*)&exs[e][i0 + i4 * 4];
            exw[i4*4+0] = xv.x; exw[i4*4+1] = xv.y; exw[i4*4+2] = xv.z; exw[i4*4+3] = xv.w;
        }
        #pragma unroll
        for (int tq = 0; tq < 16; ++tq) {
            float4 xn = *(const float4*)&exs[e][i0 + 16 + tq * 4];
            #pragma unroll
            for (int dt = 0; dt < 4; ++dt) {
                const int t = tq * 4 + dt;
                #pragma unroll
                for (int i = 0; i < 16; ++i)
                    acc[i] += w[t] * exw[(t + i) & 15];   // static indices -> registers
                exw[t & 15] = (dt == 0) ? xn.x : (dt == 1) ? xn.y : (dt == 2) ? xn.z : xn.w;
            }
        }
        const int u = e * NHID + h;
        #pragma unroll
        for (int i4 = 0; i4 < 4; ++i4) {
            float4 sv;
            sv.x = sigmoidf(acc[i4*4+0]);
            sv.y = sigmoidf(acc[i4*4+1]);
            sv.z = sigmoidf(acc[i4*4+2]);
            sv.w = sigmoidf(acc[i4*4+3]);
            *(float4*)&sig[u][i0 + i4 * 4] = sv;
        }
    }
    __syncthreads();

    // Phase 3: i = tid>>1 (0..127), half = tid&1 splits u-range and t-range.
    const int i = tid >> 1;
    const int half = tid & 1;
    float acc0 = 0.f, acc1 = 0.f;
    #pragma unroll 8
    for (int k = 0; k < 48; ++k) {
        const int u = 48 * half + k;
        float sv = sig[u][i];
        acc0 += W3[64 + u] * sv;          // W3[0][64+u]
        acc1 += W3[160 + 64 + u] * sv;    // W3[1][64+u]
    }
    #pragma unroll 1
    for (int e = 0; e < NEXO; ++e) {
        #pragma unroll 8
        for (int k = 0; k < 32; ++k) {
            const int t = 32 * half + k;
            float xv = exs[e][i + t];
            acc0 += W1[t * 5 + 2 + e] * xv;
            acc1 += W1[320 + t * 5 + 2 + e] * xv;
        }
    }
    acc0 += __shfl_xor(acc0, 1, 64);
    acc1 += __shfl_xor(acc1, 1, 64);
    if (half == 0) {
        float2 ev;
        ev.x = acc0 + b1[0] + b3[0];
        ev.y = acc1 + b1[1] + b3[1];
        *(float2*)&E[(size_t)b * (NOUT * NTGT) + i * NTGT] = ev;
    }
}

// -------------------------------------------------------------------------
// Kernel B: recurrence. ONE batch element per 64-thread (single-wave) block.
// Lane = (s = tid>>5, h = tid&31) owns hidden unit (s,h). The 64-deep target
// window lives in a 72-deep register ring (static indices; shifted by 8 every
// chunk). Hot dot does zero LDS reads. Full-wave butterfly reduce; no
// __syncthreads in the step loop.
// -------------------------------------------------------------------------
#define CH 8
#define WIN 72

__global__ __launch_bounds__(64) void narx_recur_kernel(
    const float* __restrict__ target,
    const float* __restrict__ W1,
    const float* __restrict__ W2, const float* __restrict__ b2,
    const float* __restrict__ W3,
    float* __restrict__ out)   // holds E on entry; final preds on exit
{
    __shared__ __align__(16) float ylds[NTGT][EXROWS];  // mirror for out1 reads
    __shared__ __align__(16) float e2[NOUT][NTGT];      // E, overwritten by preds

    const int tid = threadIdx.x;
    const int b = blockIdx.x;
    const int s = tid >> 5;    // series / output index
    const int h = tid & 31;    // hidden unit

    {   // init window rows 0..63 (transpose (t,s) -> [s][t])
        float2 tv = *(const float2*)&target[(size_t)b * (NIN * NTGT) + tid * 2];
        ylds[0][tid] = tv.x;
        ylds[1][tid] = tv.y;
    }
    {   // E -> e2 (flat copy)
        float4 ev = *(const float4*)&out[(size_t)b * (NOUT * NTGT) + tid * 4];
        *(float4*)&(((float*)e2)[tid * 4]) = ev;
    }
    __syncthreads();

    // per-lane weights
    float w2[NIN];
    const float* wr = W2 + (s * NHID + h) * NIN;
    #pragma unroll
    for (int t4 = 0; t4 < 16; ++t4) {
        float4 wv = *(const float4*)(wr + t4 * 4);
        w2[t4*4+0] = wv.x; w2[t4*4+1] = wv.y; w2[t4*4+2] = wv.z; w2[t4*4+3] = wv.w;
    }
    const float bb  = b2[s * NHID + h];
    const float w3a = W3[s * NHID + h];          // o=0 column
    const float w3b = W3[160 + s * NHID + h];    // o=1 column
    float w1a[2], w1b[2];                        // out1 weights for t=2h+dt, own s
    #pragma unroll
    for (int dt = 0; dt < 2; ++dt) {
        w1a[dt] = W1[(2 * h + dt) * 5 + s];
        w1b[dt] = W1[320 + (2 * h + dt) * 5 + s];
    }

    float ywin[WIN];   // rows [8c, 8c+72) of series s
    #pragma unroll
    for (int k = 0; k < NIN; ++k) ywin[k] = ylds[s][k];

    #pragma unroll 1
    for (int c = 0; c < NOUT / CH; ++c) {
        if (c > 0) {
            #pragma unroll
            for (int k = 0; k < NIN; ++k) ywin[k] = ywin[k + CH];
        }
        #pragma unroll
        for (int ci = 0; ci < CH; ++ci) {
            const int i = c * CH + ci;
            // hidden dot from registers (two interleaved chains)
            float ae = bb, ao = 0.f;
            #pragma unroll
            for (int t = 0; t < NIN; t += 2) {
                ae += w2[t]     * ywin[ci + t];
                ao += w2[t + 1] * ywin[ci + t + 1];
            }
            const float sg = sigmoidf(ae + ao);
            float v0 = w3a * sg;
            float v1 = w3b * sg;
            // out1: this lane covers t = 2h, 2h+1 of its own series
            #pragma unroll
            for (int dt = 0; dt < 2; ++dt) {
                float yv = ylds[s][i + 2 * h + dt];
                v0 += w1a[dt] * yv;
                v1 += w1b[dt] * yv;
            }
            // full-wave butterfly: sums over all (s,h) lanes
            #pragma unroll
            for (int off = 1; off <= 32; off <<= 1) {
                v0 += __shfl_xor(v0, off, 64);
                v1 += __shfl_xor(v1, off, 64);
            }
            const float ev = e2[i][s];           // read BEFORE writer overwrites
            const float vs = (s == 0) ? v0 : v1;
            const float pred = vs + ev + ywin[ci + 63];
            ywin[ci + 64] = pred;
            if (h == 0) {
                ylds[s][i + NIN] = pred;
                e2[i][s] = pred;
            }
        }
    }
    __syncthreads();
    {   // dump predictions
        float4 ev = *(const float4*)&(((float*)e2)[tid * 4]);
        *(float4*)&out[(size_t)b * (NOUT * NTGT) + tid * 4] = ev;
    }
}

extern "C" void kernel_launch(void* const* d_in, const int* in_sizes, int n_in,
                              void* d_out, int out_size, void* d_ws, size_t ws_size,
                              hipStream_t stream) {
    (void)in_sizes; (void)n_in; (void)out_size; (void)d_ws; (void)ws_size;
    const float* target = (const float*)d_in[0];
    const float* exog   = (const float*)d_in[1];
    const float* W1     = (const float*)d_in[2];
    const float* b1     = (const float*)d_in[3];
    const float* W2     = (const float*)d_in[4];
    const float* b2     = (const float*)d_in[5];
    const float* W3     = (const float*)d_in[6];
    const float* b3     = (const float*)d_in[7];
    float* out = (float*)d_out;

    hipLaunchKernelGGL(narx_exog_kernel, dim3(NB), dim3(256), 0, stream,
                       exog, W1, b1, W2, b2, W3, b3, out);
    hipLaunchKernelGGL(narx_recur_kernel, dim3(NB), dim3(64), 0, stream,
                       target, W1, W2, b2, W3, out);
}